// Round 10
// baseline (82.042 us; speedup 1.0000x reference)
//
#include <hip/hip_runtime.h>
#include <math.h>

#define NN 1536
#define DIN 256
#define DOUT 64
#define NWAY 16
#define NSUP 768
#define MR 6      // i-rows per k_esh block; 1536/6 = 256 blocks = exactly 1/CU

// d_out layout (floats): scores[768*16], h_out[1536*64], a[1536*1536]
#define OFF_SCORES 0
#define OFF_H 12288
#define OFF_A 110592

// d_ws layout (floats)
#define WG 0          // g[1536*64]
#define WQ 98304      // q[1536] (pre-scaled by 0.6)
#define WCODE 99840   // code[1536] int: known ? label : -1
#define WCENT 101376  // centroids[16*64]

// ---------------- g = hidden @ W^T, q_i = 0.6*<w, g_i>, mask code ----------------
__global__ __launch_bounds__(256) void k_g(const float* __restrict__ hid,
                                           const float* __restrict__ W,
                                           const float* __restrict__ attw,
                                           const int* __restrict__ labels,
                                           const int* __restrict__ zda,
                                           float* __restrict__ g,
                                           float* __restrict__ q,
                                           int* __restrict__ code) {
  int t = threadIdx.x;
  int r = t >> 6, d = t & 63;
  int i = blockIdx.x * 4 + r;
  const float4* hp = (const float4*)(hid + (size_t)i * DIN);
  const float4* wp = (const float4*)(W + (size_t)d * DIN);
  float4 acc = {0.f, 0.f, 0.f, 0.f};
#pragma unroll
  for (int k = 0; k < DIN / 4; k++) {
    float4 h4 = hp[k];
    float4 w4 = wp[k];
    acc.x = fmaf(h4.x, w4.x, acc.x);
    acc.y = fmaf(h4.y, w4.y, acc.y);
    acc.z = fmaf(h4.z, w4.z, acc.z);
    acc.w = fmaf(h4.w, w4.w, acc.w);
  }
  float gv = (acc.x + acc.y) + (acc.z + acc.w);
  g[(size_t)i * DOUT + d] = gv;
  float val = gv * attw[d];
#pragma unroll
  for (int off = 32; off >= 1; off >>= 1) val += __shfl_xor(val, off, 64);
  if (d == 0) q[i] = 0.6f * val;
  if (t < 4) {
    int ii = blockIdx.x * 4 + t;
    code[ii] = zda[ii] ? -1 : labels[ii];
  }
}

// ---- mega: e (3 passes, R7 wave-dim-split micro-structure) + softmax + h ----
// 256 blocks x 1024 threads (16 waves). Block owns 6 i-rows; e kept in LDS.
__global__ __launch_bounds__(1024) void k_esh(const float* __restrict__ g,
                                              const float* __restrict__ q,
                                              const int* __restrict__ code,
                                              const float* __restrict__ attw,
                                              float* __restrict__ aout,
                                              float* __restrict__ hout) {
  __shared__ float el[MR][NN];        // 36.9 KB: e, then normalized a
  __shared__ float lp[16][MR][64];    // 24 KB half-sums per pass
  __shared__ float gis[MR * DOUT];    // 1.5 KB
  __shared__ float qi[MR];
  __shared__ int ci[MR];
  __shared__ float redm[16];
  __shared__ float reds[16];

  int t = threadIdx.x;
  int lane = t & 63;
  int w = t >> 6;                 // 16 waves
  int i0 = blockIdx.x * MR;

  if (t < MR * 16) {              // 96 float4 = 6 rows x 64 floats
    ((float4*)gis)[t] = ((const float4*)(g + (size_t)i0 * DOUT))[t];
  } else if (t < MR * 16 + MR) {
    int u = t - MR * 16;
    qi[u] = q[i0 + u];
    ci[u] = code[i0 + u];
  }
  int whalf = __builtin_amdgcn_readfirstlane(w & 1);
  int jgrp = w >> 1;              // 0..7
  const float4* wv = (const float4*)(attw + whalf * 32);  // SGPR-uniform
  __syncthreads();

  // ---- phase E: 3 passes x 512 j ----
#pragma unroll 1
  for (int p = 0; p < 3; p++) {
    int j = p * 512 + jgrp * 64 + lane;
    float4 gj[8];
    const float4* gp = (const float4*)(g + (size_t)j * DOUT + whalf * 32);
#pragma unroll
    for (int k = 0; k < 8; k++) gj[k] = gp[k];
#pragma unroll 1
    for (int u = 0; u < MR; u++) {
      const float4* gv = (const float4*)(gis + u * DOUT + whalf * 32);
      float4 acc = {0.f, 0.f, 0.f, 0.f};
#pragma unroll
      for (int k = 0; k < 8; k++) {
        float4 a4 = gv[k];   // wave-uniform LDS broadcast
        float4 w4 = wv[k];   // SGPR
        float4 b4 = gj[k];
        acc.x = fmaf(w4.x, fabsf(a4.x + b4.x), acc.x);
        acc.y = fmaf(w4.y, fabsf(a4.y + b4.y), acc.y);
        acc.z = fmaf(w4.z, fabsf(a4.z + b4.z), acc.z);
        acc.w = fmaf(w4.w, fabsf(a4.w + b4.w), acc.w);
      }
      lp[w][u][lane] = (acc.x + acc.y) + (acc.z + acc.w);
    }
    __syncthreads();
    // combine halves -> e into LDS (same association as R7: half0 + half1)
    {
      int jsl = t & 511;
      int jgc = jsl >> 6;
      int ln = jsl & 63;
      int jglob = p * 512 + jsl;
      float qj = q[jglob];
      int cj = code[jglob];
      int u0 = (t >> 9) * 3;
#pragma unroll
      for (int v = 0; v < 3; v++) {
        int u = u0 + v;
        float s = lp[jgc * 2][u][ln] + lp[jgc * 2 + 1][u][ln];
        float e = (qi[u] + qj) + 0.4f * s;
        int cu = ci[u];
        if ((cu >= 0) && (cj >= 0) && (cu != cj)) e = -1e30f;
        el[u][jglob] = e;
      }
    }
    __syncthreads();   // lp reused next pass
  }

  // ---- phase SM: row softmax in LDS; write a to global ----
#pragma unroll 1
  for (int r = 0; r < MR; r++) {
    float v0 = el[r][t];
    float v1 = (t < 512) ? el[r][1024 + t] : -3.0e38f;
    float m = fmaxf(v0, v1);
#pragma unroll
    for (int off = 32; off >= 1; off >>= 1) m = fmaxf(m, __shfl_xor(m, off, 64));
    if (lane == 0) redm[w] = m;
    __syncthreads();
    m = redm[0];
#pragma unroll
    for (int k = 1; k < 16; k++) m = fmaxf(m, redm[k]);
    float e0 = __expf(v0 - m);
    float e1 = (t < 512) ? __expf(v1 - m) : 0.f;
    float s = e0 + e1;
#pragma unroll
    for (int off = 32; off >= 1; off >>= 1) s += __shfl_xor(s, off, 64);
    if (lane == 0) reds[w] = s;
    __syncthreads();
    s = reds[0];
#pragma unroll
    for (int k = 1; k < 16; k++) s += reds[k];
    float inv = 1.f / s;
    e0 *= inv;
    el[r][t] = e0;
    aout[(size_t)(i0 + r) * NN + t] = e0;
    if (t < 512) {
      e1 *= inv;
      el[r][1024 + t] = e1;
      aout[(size_t)(i0 + r) * NN + 1024 + t] = e1;
    }
  }
  __syncthreads();   // all a values in LDS before phase H

  // ---- phase H: wave w owns d-cols [w*4, w*4+4); lanes split j; shfl-tree reduce ----
  float4 acc0 = {0,0,0,0}, acc1 = {0,0,0,0}, acc2 = {0,0,0,0};
  float4 acc3 = {0,0,0,0}, acc4 = {0,0,0,0}, acc5 = {0,0,0,0};
#pragma unroll 4
  for (int jj = 0; jj < NN / 64; jj++) {
    int j = jj * 64 + lane;
    float4 g4 = *(const float4*)(g + (size_t)j * DOUT + w * 4);
    float a0 = el[0][j], a1 = el[1][j], a2 = el[2][j];
    float a3 = el[3][j], a4 = el[4][j], a5 = el[5][j];
    acc0.x = fmaf(a0, g4.x, acc0.x); acc0.y = fmaf(a0, g4.y, acc0.y);
    acc0.z = fmaf(a0, g4.z, acc0.z); acc0.w = fmaf(a0, g4.w, acc0.w);
    acc1.x = fmaf(a1, g4.x, acc1.x); acc1.y = fmaf(a1, g4.y, acc1.y);
    acc1.z = fmaf(a1, g4.z, acc1.z); acc1.w = fmaf(a1, g4.w, acc1.w);
    acc2.x = fmaf(a2, g4.x, acc2.x); acc2.y = fmaf(a2, g4.y, acc2.y);
    acc2.z = fmaf(a2, g4.z, acc2.z); acc2.w = fmaf(a2, g4.w, acc2.w);
    acc3.x = fmaf(a3, g4.x, acc3.x); acc3.y = fmaf(a3, g4.y, acc3.y);
    acc3.z = fmaf(a3, g4.z, acc3.z); acc3.w = fmaf(a3, g4.w, acc3.w);
    acc4.x = fmaf(a4, g4.x, acc4.x); acc4.y = fmaf(a4, g4.y, acc4.y);
    acc4.z = fmaf(a4, g4.z, acc4.z); acc4.w = fmaf(a4, g4.w, acc4.w);
    acc5.x = fmaf(a5, g4.x, acc5.x); acc5.y = fmaf(a5, g4.y, acc5.y);
    acc5.z = fmaf(a5, g4.z, acc5.z); acc5.w = fmaf(a5, g4.w, acc5.w);
  }
#pragma unroll
  for (int off = 32; off >= 1; off >>= 1) {
    acc0.x += __shfl_xor(acc0.x, off, 64); acc0.y += __shfl_xor(acc0.y, off, 64);
    acc0.z += __shfl_xor(acc0.z, off, 64); acc0.w += __shfl_xor(acc0.w, off, 64);
    acc1.x += __shfl_xor(acc1.x, off, 64); acc1.y += __shfl_xor(acc1.y, off, 64);
    acc1.z += __shfl_xor(acc1.z, off, 64); acc1.w += __shfl_xor(acc1.w, off, 64);
    acc2.x += __shfl_xor(acc2.x, off, 64); acc2.y += __shfl_xor(acc2.y, off, 64);
    acc2.z += __shfl_xor(acc2.z, off, 64); acc2.w += __shfl_xor(acc2.w, off, 64);
    acc3.x += __shfl_xor(acc3.x, off, 64); acc3.y += __shfl_xor(acc3.y, off, 64);
    acc3.z += __shfl_xor(acc3.z, off, 64); acc3.w += __shfl_xor(acc3.w, off, 64);
    acc4.x += __shfl_xor(acc4.x, off, 64); acc4.y += __shfl_xor(acc4.y, off, 64);
    acc4.z += __shfl_xor(acc4.z, off, 64); acc4.w += __shfl_xor(acc4.w, off, 64);
    acc5.x += __shfl_xor(acc5.x, off, 64); acc5.y += __shfl_xor(acc5.y, off, 64);
    acc5.z += __shfl_xor(acc5.z, off, 64); acc5.w += __shfl_xor(acc5.w, off, 64);
  }
  if (lane == 0) {
    *(float4*)(hout + (size_t)(i0 + 0) * DOUT + w * 4) = acc0;
    *(float4*)(hout + (size_t)(i0 + 1) * DOUT + w * 4) = acc1;
    *(float4*)(hout + (size_t)(i0 + 2) * DOUT + w * 4) = acc2;
    *(float4*)(hout + (size_t)(i0 + 3) * DOUT + w * 4) = acc3;
    *(float4*)(hout + (size_t)(i0 + 4) * DOUT + w * 4) = acc4;
    *(float4*)(hout + (size_t)(i0 + 5) * DOUT + w * 4) = acc5;
  }
}

// ---------------- centroids (one block per class, 1024 threads) ----------------
__global__ __launch_bounds__(1024) void k_cent(const float* __restrict__ h,
                                               const int* __restrict__ labels,
                                               float* __restrict__ cent) {
  __shared__ float part[16][64];
  __shared__ int pc[16];
  int c = blockIdx.x, t = threadIdx.x;
  int d = t & 63, rq = t >> 6;
  float acc = 0.f;
  int cnt = 0;
#pragma unroll 4
  for (int r = rq; r < NSUP; r += 16) {
    int lab = labels[r];
    if (lab == c) { acc += h[(size_t)r * DOUT + d]; cnt++; }
  }
  part[rq][d] = acc;
  if (d == 0) pc[rq] = cnt;
  __syncthreads();
  if (t < 64) {
    float num = 0.f;
    int count = 0;
#pragma unroll
    for (int k = 0; k < 16; k++) { num += part[k][t]; count += pc[k]; }
    cent[c * DOUT + t] = (count > 0) ? (num / (float)count) : 0.f;
  }
}

// ---------------- scores = 1/(dist(query, centroid)+1e-10) ----------------
__global__ __launch_bounds__(256) void k_scores(const float* __restrict__ h,
                                                const float* __restrict__ cent,
                                                float* __restrict__ scores) {
  __shared__ float cl[NWAY * 65];
  __shared__ float hl[16 * 65];
  int t = threadIdx.x;
  int q0 = blockIdx.x * 16;
#pragma unroll
  for (int u = 0; u < 4; u++) {
    int f = t + u * 256;
    int row = f >> 6, k = f & 63;
    cl[row * 65 + k] = cent[f];
    hl[row * 65 + k] = h[(size_t)(NSUP + q0) * DOUT + f];
  }
  __syncthreads();
  int qr = t >> 4, c = t & 15;
  const float* hv = hl + qr * 65;
  const float* cv = cl + c * 65;
  float hh = 0.f, cc = 0.f, hc = 0.f;
#pragma unroll
  for (int k = 0; k < DOUT; k++) {
    float av = hv[k], bv = cv[k];
    hh = fmaf(av, av, hh);
    cc = fmaf(bv, bv, cc);
    hc = fmaf(av, bv, hc);
  }
  float d2 = fmaxf(hh + cc - 2.f * hc, 0.f);
  scores[q0 * NWAY + t] = 1.f / (sqrtf(d2) + 1e-10f);
}

extern "C" void kernel_launch(void* const* d_in, const int* in_sizes, int n_in,
                              void* d_out, int out_size, void* d_ws, size_t ws_size,
                              hipStream_t stream) {
  const float* hid = (const float*)d_in[0];
  const float* W = (const float*)d_in[1];
  const float* attw = (const float*)d_in[2];
  const int* labels = (const int*)d_in[3];
  const int* zda = (const int*)d_in[4];
  float* out = (float*)d_out;
  float* ws = (float*)d_ws;

  float* g = ws + WG;
  float* q = ws + WQ;
  int* code = (int*)(ws + WCODE);
  float* cent = ws + WCENT;
  float* scores = out + OFF_SCORES;
  float* h = out + OFF_H;
  float* a = out + OFF_A;

  hipLaunchKernelGGL(k_g, dim3(NN / 4), dim3(256), 0, stream, hid, W, attw, labels, zda, g, q, code);
  hipLaunchKernelGGL(k_esh, dim3(NN / MR), dim3(1024), 0, stream, g, q, code, attw, a, h);
  hipLaunchKernelGGL(k_cent, dim3(NWAY), dim3(1024), 0, stream, h, labels, cent);
  hipLaunchKernelGGL(k_scores, dim3(NSUP / 16), dim3(256), 0, stream, h, cent, scores);
}

// Round 11
// 70.101 us; speedup vs baseline: 1.1703x; 1.1703x over previous
//
#include <hip/hip_runtime.h>
#include <math.h>

#define NN 1536
#define DIN 256
#define DOUT 64
#define NWAY 16
#define NSUP 768
#define IB 12     // i-rows per k_e block; grid (128, 6) = 768 = 3 blocks/CU
#define JBLK 256  // j per k_e block: 4 waves x 64 lanes x 4 j (each wave owns a dim-quarter)
#define SROWS 3   // rows per k_smh block; 1536/3 = 512 blocks = 2/CU

// d_out layout (floats): scores[768*16], h_out[1536*64], a[1536*1536]
#define OFF_SCORES 0
#define OFF_H 12288
#define OFF_A 110592

// d_ws layout (floats)
#define WG 0          // g[1536*64]
#define WQ 98304      // q[1536] (pre-scaled by 0.6)
#define WCODE 99840   // code[1536] int: known ? label : -1
#define WCENT 101376  // centroids[16*64]

// ---------------- g = hidden @ W^T, q_i = 0.6*<w, g_i>, mask code ----------------
__global__ __launch_bounds__(256) void k_g(const float* __restrict__ hid,
                                           const float* __restrict__ W,
                                           const float* __restrict__ attw,
                                           const int* __restrict__ labels,
                                           const int* __restrict__ zda,
                                           float* __restrict__ g,
                                           float* __restrict__ q,
                                           int* __restrict__ code) {
  int t = threadIdx.x;
  int r = t >> 6, d = t & 63;
  int i = blockIdx.x * 4 + r;
  const float4* hp = (const float4*)(hid + (size_t)i * DIN);
  const float4* wp = (const float4*)(W + (size_t)d * DIN);
  float4 acc = {0.f, 0.f, 0.f, 0.f};
#pragma unroll
  for (int k = 0; k < DIN / 4; k++) {
    float4 h4 = hp[k];
    float4 w4 = wp[k];
    acc.x = fmaf(h4.x, w4.x, acc.x);
    acc.y = fmaf(h4.y, w4.y, acc.y);
    acc.z = fmaf(h4.z, w4.z, acc.z);
    acc.w = fmaf(h4.w, w4.w, acc.w);
  }
  float gv = (acc.x + acc.y) + (acc.z + acc.w);
  g[(size_t)i * DOUT + d] = gv;
  float val = gv * attw[d];
#pragma unroll
  for (int off = 32; off >= 1; off >>= 1) val += __shfl_xor(val, off, 64);
  if (d == 0) q[i] = 0.6f * val;
  if (t < 4) {
    int ii = blockIdx.x * 4 + t;
    code[ii] = zda[ii] ? -1 : labels[ii];
  }
}

// ---- e[i][j]: wave owns dim-quarter (w), thread owns FOUR j's ----
// One ds_read_b128 of g_i feeds 32 VALU ops -> LDS pipe demand < VALU demand.
__global__ __launch_bounds__(256, 2) void k_e(const float* __restrict__ g,
                                              const float* __restrict__ q,
                                              const int* __restrict__ code,
                                              const float* __restrict__ attw,
                                              float* __restrict__ aout) {
  __shared__ float gis[IB * DOUT];      // 3 KB
  __shared__ float lp[4][IB][JBLK];     // 48 KB quarter-sums
  __shared__ float qi[IB];
  __shared__ int ci[IB];
  int t = threadIdx.x;
  int lane = t & 63;
  int w = t >> 6;                            // 4 waves
  int wq = __builtin_amdgcn_readfirstlane(w); // dim-quarter 0..3
  int i0 = blockIdx.x * IB;
  int j0 = blockIdx.y * JBLK;

  if (t < IB * 16) {                     // 192 float4 = 12 rows x 64
    ((float4*)gis)[t] = ((const float4*)(g + (size_t)i0 * DOUT))[t];
  } else if (t < IB * 16 + IB) {
    int u = t - IB * 16;
    qi[u] = q[i0 + u];
    ci[u] = code[i0 + u];
  }
  float4 gj0[4], gj1[4], gj2[4], gj3[4];
  {
    const float4* p0 = (const float4*)(g + (size_t)(j0 + lane) * DOUT + wq * 16);
    const float4* p1 = (const float4*)(g + (size_t)(j0 + 64 + lane) * DOUT + wq * 16);
    const float4* p2 = (const float4*)(g + (size_t)(j0 + 128 + lane) * DOUT + wq * 16);
    const float4* p3 = (const float4*)(g + (size_t)(j0 + 192 + lane) * DOUT + wq * 16);
#pragma unroll
    for (int k = 0; k < 4; k++) gj0[k] = p0[k];
#pragma unroll
    for (int k = 0; k < 4; k++) gj1[k] = p1[k];
#pragma unroll
    for (int k = 0; k < 4; k++) gj2[k] = p2[k];
#pragma unroll
    for (int k = 0; k < 4; k++) gj3[k] = p3[k];
  }
  const float4* wv = (const float4*)(attw + wq * 16);  // SGPR-uniform
  __syncthreads();

#pragma unroll 1
  for (int u = 0; u < IB; u++) {
    const float4* gv = (const float4*)(gis + u * DOUT + wq * 16);
    float4 a0 = {0,0,0,0}, a1 = {0,0,0,0}, a2 = {0,0,0,0}, a3 = {0,0,0,0};
#pragma unroll
    for (int k = 0; k < 4; k++) {
      float4 a4 = gv[k];   // wave-uniform LDS broadcast (1 read -> 4 j's)
      float4 w4 = wv[k];   // SGPR
      float4 b;
      b = gj0[k];
      a0.x = fmaf(w4.x, fabsf(a4.x + b.x), a0.x);
      a0.y = fmaf(w4.y, fabsf(a4.y + b.y), a0.y);
      a0.z = fmaf(w4.z, fabsf(a4.z + b.z), a0.z);
      a0.w = fmaf(w4.w, fabsf(a4.w + b.w), a0.w);
      b = gj1[k];
      a1.x = fmaf(w4.x, fabsf(a4.x + b.x), a1.x);
      a1.y = fmaf(w4.y, fabsf(a4.y + b.y), a1.y);
      a1.z = fmaf(w4.z, fabsf(a4.z + b.z), a1.z);
      a1.w = fmaf(w4.w, fabsf(a4.w + b.w), a1.w);
      b = gj2[k];
      a2.x = fmaf(w4.x, fabsf(a4.x + b.x), a2.x);
      a2.y = fmaf(w4.y, fabsf(a4.y + b.y), a2.y);
      a2.z = fmaf(w4.z, fabsf(a4.z + b.z), a2.z);
      a2.w = fmaf(w4.w, fabsf(a4.w + b.w), a2.w);
      b = gj3[k];
      a3.x = fmaf(w4.x, fabsf(a4.x + b.x), a3.x);
      a3.y = fmaf(w4.y, fabsf(a4.y + b.y), a3.y);
      a3.z = fmaf(w4.z, fabsf(a4.z + b.z), a3.z);
      a3.w = fmaf(w4.w, fabsf(a4.w + b.w), a3.w);
    }
    lp[w][u][lane] = (a0.x + a0.y) + (a0.z + a0.w);
    lp[w][u][lane + 64] = (a1.x + a1.y) + (a1.z + a1.w);
    lp[w][u][lane + 128] = (a2.x + a2.y) + (a2.z + a2.w);
    lp[w][u][lane + 192] = (a3.x + a3.y) + (a3.z + a3.w);
  }
  __syncthreads();

  // combine quarters: thread t owns j-slot t
  int jg = j0 + t;
  float qj = q[jg];
  int cj = code[jg];
#pragma unroll
  for (int u = 0; u < IB; u++) {
    float s = (lp[0][u][t] + lp[1][u][t]) + (lp[2][u][t] + lp[3][u][t]);
    float e = (qi[u] + qj) + 0.4f * s;
    int cu = ci[u];
    if ((cu >= 0) && (cj >= 0) && (cu != cj)) e = -1e30f;
    aout[(size_t)(i0 + u) * NN + jg] = e;
  }
}

// ---- fused: row softmax (in-place on a) + h = a @ g, 3 rows per block ----
// part[] overlays al[] (union buffer) after all al reads complete -> LDS 26KB, 2 blocks/CU.
__global__ __launch_bounds__(512) void k_smh(float* __restrict__ a,
                                             const float* __restrict__ g,
                                             float* __restrict__ h) {
  __shared__ float buf[32 * SROWS * 68];   // 26.1 KB: al[3][1536] (18.4KB) then part[32][3][68]
  __shared__ float red[16];
  float* al = buf;
  int t = threadIdx.x;      // 0..511
  int lane = t & 63;
  int w = t >> 6;           // 8 waves
  int r0 = blockIdx.x * SROWS;

#pragma unroll 1
  for (int r = 0; r < SROWS; r++) {
    float* row = a + (size_t)(r0 + r) * NN;
    float v0 = row[t], v1 = row[t + 512], v2 = row[t + 1024];
    float m = fmaxf(fmaxf(v0, v1), v2);
#pragma unroll
    for (int off = 32; off >= 1; off >>= 1) m = fmaxf(m, __shfl_xor(m, off, 64));
    if (lane == 0) red[w] = m;
    __syncthreads();
    m = red[0];
#pragma unroll
    for (int k = 1; k < 8; k++) m = fmaxf(m, red[k]);
    v0 = __expf(v0 - m);
    v1 = __expf(v1 - m);
    v2 = __expf(v2 - m);
    float s = (v0 + v1) + v2;
#pragma unroll
    for (int off = 32; off >= 1; off >>= 1) s += __shfl_xor(s, off, 64);
    if (lane == 0) red[8 + w] = s;
    __syncthreads();
    s = red[8];
#pragma unroll
    for (int k = 1; k < 8; k++) s += red[8 + k];
    float inv = 1.f / s;
    v0 *= inv; v1 *= inv; v2 *= inv;
    al[r * NN + t] = v0; al[r * NN + 512 + t] = v1; al[r * NN + 1024 + t] = v2;
    row[t] = v0; row[t + 512] = v1; row[t + 1024] = v2;
    __syncthreads();
  }

  // --- h-phase: 32-way j split; thread (jr,dq) streams g[j][dq*4..] ---
  int jr = t >> 4;     // 0..31
  int dq = t & 15;
  float4 acc0 = {0,0,0,0}, acc1 = {0,0,0,0}, acc2 = {0,0,0,0};
#pragma unroll 4
  for (int jj = 0; jj < NN / 32; jj++) {
    int j = jj * 32 + jr;
    float4 g4 = *(const float4*)(g + (size_t)j * DOUT + dq * 4);
    float a0 = al[j], a1 = al[NN + j], a2 = al[2 * NN + j];
    acc0.x = fmaf(a0, g4.x, acc0.x); acc0.y = fmaf(a0, g4.y, acc0.y);
    acc0.z = fmaf(a0, g4.z, acc0.z); acc0.w = fmaf(a0, g4.w, acc0.w);
    acc1.x = fmaf(a1, g4.x, acc1.x); acc1.y = fmaf(a1, g4.y, acc1.y);
    acc1.z = fmaf(a1, g4.z, acc1.z); acc1.w = fmaf(a1, g4.w, acc1.w);
    acc2.x = fmaf(a2, g4.x, acc2.x); acc2.y = fmaf(a2, g4.y, acc2.y);
    acc2.z = fmaf(a2, g4.z, acc2.z); acc2.w = fmaf(a2, g4.w, acc2.w);
  }
  __syncthreads();   // all al reads done before overlaying part
  *(float4*)(&buf[(jr * SROWS + 0) * 68 + dq * 4]) = acc0;
  *(float4*)(&buf[(jr * SROWS + 1) * 68 + dq * 4]) = acc1;
  *(float4*)(&buf[(jr * SROWS + 2) * 68 + dq * 4]) = acc2;
  __syncthreads();
  if (t < SROWS * DOUT) {
    int r = t >> 6, d = t & 63;
    float s = 0.f;
#pragma unroll
    for (int k = 0; k < 32; k++) s += buf[(k * SROWS + r) * 68 + d];
    h[(size_t)(r0 + r) * DOUT + d] = s;
  }
}

// ---------------- centroids (one block per class, 1024 threads) ----------------
__global__ __launch_bounds__(1024) void k_cent(const float* __restrict__ h,
                                               const int* __restrict__ labels,
                                               float* __restrict__ cent) {
  __shared__ float part[16][64];
  __shared__ int pc[16];
  int c = blockIdx.x, t = threadIdx.x;
  int d = t & 63, rq = t >> 6;
  float acc = 0.f;
  int cnt = 0;
#pragma unroll 4
  for (int r = rq; r < NSUP; r += 16) {
    int lab = labels[r];
    if (lab == c) { acc += h[(size_t)r * DOUT + d]; cnt++; }
  }
  part[rq][d] = acc;
  if (d == 0) pc[rq] = cnt;
  __syncthreads();
  if (t < 64) {
    float num = 0.f;
    int count = 0;
#pragma unroll
    for (int k = 0; k < 16; k++) { num += part[k][t]; count += pc[k]; }
    cent[c * DOUT + t] = (count > 0) ? (num / (float)count) : 0.f;
  }
}

// ---------------- scores = 1/(dist(query, centroid)+1e-10) ----------------
__global__ __launch_bounds__(256) void k_scores(const float* __restrict__ h,
                                                const float* __restrict__ cent,
                                                float* __restrict__ scores) {
  __shared__ float cl[NWAY * 65];
  __shared__ float hl[16 * 65];
  int t = threadIdx.x;
  int q0 = blockIdx.x * 16;
#pragma unroll
  for (int u = 0; u < 4; u++) {
    int f = t + u * 256;
    int row = f >> 6, k = f & 63;
    cl[row * 65 + k] = cent[f];
    hl[row * 65 + k] = h[(size_t)(NSUP + q0) * DOUT + f];
  }
  __syncthreads();
  int qr = t >> 4, c = t & 15;
  const float* hv = hl + qr * 65;
  const float* cv = cl + c * 65;
  float hh = 0.f, cc = 0.f, hc = 0.f;
#pragma unroll
  for (int k = 0; k < DOUT; k++) {
    float av = hv[k], bv = cv[k];
    hh = fmaf(av, av, hh);
    cc = fmaf(bv, bv, cc);
    hc = fmaf(av, bv, hc);
  }
  float d2 = fmaxf(hh + cc - 2.f * hc, 0.f);
  scores[q0 * NWAY + t] = 1.f / (sqrtf(d2) + 1e-10f);
}

extern "C" void kernel_launch(void* const* d_in, const int* in_sizes, int n_in,
                              void* d_out, int out_size, void* d_ws, size_t ws_size,
                              hipStream_t stream) {
  const float* hid = (const float*)d_in[0];
  const float* W = (const float*)d_in[1];
  const float* attw = (const float*)d_in[2];
  const int* labels = (const int*)d_in[3];
  const int* zda = (const int*)d_in[4];
  float* out = (float*)d_out;
  float* ws = (float*)d_ws;

  float* g = ws + WG;
  float* q = ws + WQ;
  int* code = (int*)(ws + WCODE);
  float* cent = ws + WCENT;
  float* scores = out + OFF_SCORES;
  float* h = out + OFF_H;
  float* a = out + OFF_A;

  hipLaunchKernelGGL(k_g, dim3(NN / 4), dim3(256), 0, stream, hid, W, attw, labels, zda, g, q, code);
  hipLaunchKernelGGL(k_e, dim3(NN / IB, NN / JBLK), dim3(256), 0, stream, g, q, code, attw, a);
  hipLaunchKernelGGL(k_smh, dim3(NN / SROWS), dim3(512), 0, stream, a, g, h);
  hipLaunchKernelGGL(k_cent, dim3(NWAY), dim3(1024), 0, stream, h, labels, cent);
  hipLaunchKernelGGL(k_scores, dim3(NSUP / 16), dim3(256), 0, stream, h, cent, scores);
}